// Round 8
// baseline (115.556 us; speedup 1.0000x reference)
//
#include <hip/hip_runtime.h>
#include <math.h>

#define N      512
#define RNUM   4
#define BNUM   2
#define NSLICE (RNUM * BNUM)
#define TILE   128               // (a,b) tile 128x128, 256 threads x (8x8)
#define CT     32                // c-chunk per LDS buffer
#define LSTR   136               // f16 row stride (272 B) - bank-verified
#define CSPLIT 8                 // c-split -> 1024 main blocks, 2 chunks each
#define NCOLB  16                // colsum-role blocks (8 slices x 2 halves)
#define SCALE  0.0625f           // (1/2 relu-split) * (1/8 weight/(R*B))

typedef _Float16 half2_t __attribute__((ext_vector_type(2)));

__device__ __forceinline__ unsigned int h2u(half2_t h) {
  return __builtin_bit_cast(unsigned int, h);
}
__device__ __forceinline__ half2_t u2h(unsigned int u) {
  return __builtin_bit_cast(half2_t, u);
}

#if __has_builtin(__builtin_amdgcn_fdot2)
__device__ __forceinline__ float fdot2_(half2_t a, half2_t b, float c) {
  return __builtin_amdgcn_fdot2(a, b, c, false);
}
#else
__device__ __forceinline__ float fdot2_(half2_t a, half2_t b, float c) {
  return c + (float)a.x * (float)b.x + (float)a.y * (float)b.y;
}
#endif

__device__ __forceinline__ float sigmoidf_(float x) {
  return 1.0f / (1.0f + __expf(-x));
}

__device__ __forceinline__ unsigned packh2(float a, float b) {
  half2_t h = {(_Float16)a, (_Float16)b};
  return h2u(h);
}

__global__ void zero_out_kernel(float* out) { out[0] = 0.0f; }

// prep: one thread per (b,i,4xj): 64B contiguous logits load (4x float4),
// 16 sigmoids, per-plane 8B packed store (uint2 of 4 f16). P stays f16 (4MB).
__global__ __launch_bounds__(256) void prep_f16_kernel(const float* __restrict__ logits,
                                                       const int* __restrict__ masks,
                                                       _Float16* __restrict__ P,
                                                       float* __restrict__ out) {
  if (blockIdx.x == 0 && threadIdx.x == 0) out[0] = 0.0f;
  int t = blockIdx.x * 256 + threadIdx.x;      // 0 .. B*N*N/4 - 1
  int b = t >> 16;                              // / (N*N/4)
  int rem4 = t & (N * N / 4 - 1);
  int i = rem4 >> 7;                            // row
  int j4 = rem4 & 127;                          // j-group (j = 4*j4)
  const float4* Lp = ((const float4*)logits) + ((size_t)(b * N + i) * N + 4 * j4);
  float4 l0 = Lp[0], l1 = Lp[1], l2 = Lp[2], l3 = Lp[3];
  int4 mj = *(const int4*)(masks + b * N + 4 * j4);
  float mi = (masks[b * N + i] > 0) ? 1.0f : 0.0f;
  float m0 = mi * ((mj.x > 0) ? 1.0f : 0.0f);
  float m1 = mi * ((mj.y > 0) ? 1.0f : 0.0f);
  float m2 = mi * ((mj.z > 0) ? 1.0f : 0.0f);
  float m3 = mi * ((mj.w > 0) ? 1.0f : 0.0f);
  size_t off = (size_t)i * N + 4 * j4;
  _Float16* Pb = P + (size_t)b * RNUM * N * N + off;
  {
    uint2 v = {packh2(m0 * sigmoidf_(l0.x), m1 * sigmoidf_(l1.x)),
               packh2(m2 * sigmoidf_(l2.x), m3 * sigmoidf_(l3.x))};
    *(uint2*)(Pb + 0 * (size_t)N * N) = v;
  }
  {
    uint2 v = {packh2(m0 * sigmoidf_(l0.y), m1 * sigmoidf_(l1.y)),
               packh2(m2 * sigmoidf_(l2.y), m3 * sigmoidf_(l3.y))};
    *(uint2*)(Pb + 1 * (size_t)N * N) = v;
  }
  {
    uint2 v = {packh2(m0 * sigmoidf_(l0.z), m1 * sigmoidf_(l1.z)),
               packh2(m2 * sigmoidf_(l2.z), m3 * sigmoidf_(l3.z))};
    *(uint2*)(Pb + 2 * (size_t)N * N) = v;
  }
  {
    uint2 v = {packh2(m0 * sigmoidf_(l0.w), m1 * sigmoidf_(l1.w)),
               packh2(m2 * sigmoidf_(l2.w), m3 * sigmoidf_(l3.w))};
    *(uint2*)(Pb + 3 * (size_t)N * N) = v;
  }
}

// R16 journal — final structural probe. 8 variants pinned at 59.4-63.6us:
// busy = 42us (ISA floor: 3 VOP3P / 2 elems @ 4cyc), idle ~17us invariant to
// occupancy (27-61%), inst count (-7%), regalloc, asm. Last untested lever:
// prologue/tail amortization with CORRECT pipeline ordering. R6's dbuf failed
// mechanically: chunk-1 ds_writes (vmcnt drain) sat BEFORE compute(buf0), so
// staging latency was never hidden and 2x LDS cut occupancy for nothing.
// R16 = 3-phase ordering:
//   load0+rab -> write0 -> bar -> ISSUE load1 -> compute(buf0)
//   -> write1 (drains vmcnt after ~14k cyc of compute) -> bar -> compute(buf1)
// CSPLIT=8: 1024 blocks, half the prologues/tails; LDS 34.8KB -> 4 blocks/CU
// (wall has been occupancy-invariant; R2's 8-block config only measured 45%).
// DECISION RULE: work < 57us => prologue exposure was the idle, keep going.
// work >= 59us => idle is structural (launch ramp + barrier skew); kernel is
// at its compute floor; declare ceiling: busy floor 42us =
// 1.07e9 elems x 1.5 VOP3P/elem x 4cyc / 1024 SIMDs @ 2.4GHz, plus ~54us
// kernel-invariant e2e overhead (e2e - work constant across all 8 rounds).
__global__ __launch_bounds__(256, 4) void work_f16_kernel(const _Float16* __restrict__ P,
                                                          float* __restrict__ out) {
  __shared__ __align__(16) _Float16 tA[2][CT][LSTR];
  __shared__ __align__(16) _Float16 tB[2][CT][LSTR];
  __shared__ float wsum[4];

  const int tid = threadIdx.x;
  const int bid = blockIdx.x;

  if (bid < NCOLB) {
    // ---- colsum role: Sum_c csum_c*(N-csum_c) (factorized linear half) ----
    const int s    = bid >> 1;
    const int half = bid & 1;
    const int c    = half * 256 + tid;
    const _Float16* col = P + (size_t)s * N * N + c;
    float sum = 0.0f;
#pragma unroll 16
    for (int a = 0; a < N; ++a) sum += (float)col[(size_t)a * N];
    float v = sum * ((float)N - sum);
    for (int off = 32; off > 0; off >>= 1) v += __shfl_down(v, off, 64);
    const int wid = tid >> 6;
    if ((tid & 63) == 0) wsum[wid] = v;
    __syncthreads();
    if (tid == 0)
      atomicAdd(out, (wsum[0] + wsum[1] + wsum[2] + wsum[3]) * SCALE);
    return;
  }

  // ---- main role: Sum |rab - a_c*b_c| (abs half), packed f16 ----
  const int m  = bid - NCOLB;
  const int bt = m & 3;
  const int at = (m >> 2) & 3;
  const int s  = (m >> 4) & 7;
  const int cz = m >> 7;                    // 0..CSPLIT-1
  const int a0 = at * TILE;
  const int b0 = bt * TILE;
  const int c0 = cz * (2 * CT);             // two CT-chunks per block

  const int ta = tid & 15;    // a cols: a0 + ta*8 + {0..7}
  const int tb = tid >> 4;    // b cols: b0 + tb*8 + {0..7}

  const _Float16* Ph = P + (size_t)s * N * N;

  // staging geometry: thread transposes a ROW-PAIR (2 rows) x 16 c's,
  // packing {row0[c],row1[c]} u32 into an LDS column pair (2p, 2p+1).
  // Writes: 64 consecutive dwords per wave = 2-way bank alias = free.
  const int su   = tid & 127;
  const int sh   = tid >> 7;
  const int sisB = su >> 6;
  const int sp   = su & 63;                 // pair index within tile
  const int srow = (sisB ? b0 : a0) + 2 * sp;
  const _Float16* sbase = Ph + (size_t)srow * N + sh * 16;

  // ---- phase 0: issue chunk-0 staging loads + all rab loads ----
  const _Float16* s0row = sbase + c0;
  const _Float16* s1row = s0row + N;
  uint4 q0  = ((const uint4*)s0row)[0];
  uint4 q1  = ((const uint4*)s0row)[1];
  uint4 r0v = ((const uint4*)s1row)[0];
  uint4 r1v = ((const uint4*)s1row)[1];

  half2_t rab2[8][4];
#pragma unroll
  for (int x = 0; x < 8; ++x) {
    int ga = a0 + ta * 8 + x;
    uint4 q = *(const uint4*)(Ph + (size_t)ga * N + b0 + tb * 8);
    rab2[x][0] = u2h(q.x); rab2[x][1] = u2h(q.y);
    rab2[x][2] = u2h(q.z); rab2[x][3] = u2h(q.w);
  }

#define WRITE_CHUNK(buf, a0q, a1q, b0q, b1q)                                   \
  {                                                                            \
    _Float16* dst = sisB ? &tB[buf][sh * 16][2 * sp] : &tA[buf][sh * 16][2 * sp]; \
    unsigned int w0[8] = {(a0q).x, (a0q).y, (a0q).z, (a0q).w,                  \
                          (a1q).x, (a1q).y, (a1q).z, (a1q).w};                 \
    unsigned int w1[8] = {(b0q).x, (b0q).y, (b0q).z, (b0q).w,                  \
                          (b1q).x, (b1q).y, (b1q).z, (b1q).w};                 \
    _Pragma("unroll")                                                          \
    for (int k = 0; k < 8; ++k) {                                              \
      unsigned int lo = (w1[k] << 16) | (w0[k] & 0xFFFFu);                     \
      unsigned int hi = (w1[k] & 0xFFFF0000u) | (w0[k] >> 16);                 \
      *(unsigned int*)(dst + (size_t)(2 * k) * LSTR)     = lo;                 \
      *(unsigned int*)(dst + (size_t)(2 * k + 1) * LSTR) = hi;                 \
    }                                                                          \
  }

  // write chunk 0 (waits on its 4 loads; rab may still be in flight)
  WRITE_CHUNK(0, q0, q1, r0v, r1v)

  float acc[8];
#pragma unroll
  for (int x = 0; x < 8; ++x) acc[x] = 0.0f;

  const half2_t kOne = {(_Float16)1.0f, (_Float16)1.0f};

  __syncthreads();   // bar0: buf0 ready

  // ---- phase 1: issue chunk-1 staging loads (registers only — latency
  //      hides under compute(buf0)); write them to buf1 AFTER compute ----
  const _Float16* t0row = sbase + c0 + CT;
  const _Float16* t1row = t0row + N;
  uint4 p0  = ((const uint4*)t0row)[0];
  uint4 p1  = ((const uint4*)t0row)[1];
  uint4 s0v = ((const uint4*)t1row)[0];
  uint4 s1v = ((const uint4*)t1row)[1];

#define COMPUTE_CHUNK(buf)                                                     \
  _Pragma("unroll 4")                                                          \
  for (int c = 0; c < CT; ++c) {                                               \
    uint4 ua = *(const uint4*)&tA[buf][c][ta * 8];                             \
    uint4 ub = *(const uint4*)&tB[buf][c][tb * 8];                             \
    half2_t av[4] = {u2h(ua.x), u2h(ua.y), u2h(ua.z), u2h(ua.w)};              \
    half2_t bv[4] = {u2h(ub.x), u2h(ub.y), u2h(ub.z), u2h(ub.w)};              \
    _Pragma("unroll")                                                          \
    for (int x = 0; x < 8; ++x) {                                              \
      _Float16 as = (x & 1) ? av[x >> 1].y : av[x >> 1].x;                     \
      half2_t asp = {as, as};                                                  \
      float a_ = acc[x];                                                       \
      _Pragma("unroll")                                                        \
      for (int yp = 0; yp < 4; ++yp) {                                         \
        half2_t t2 = rab2[x][yp] - asp * bv[yp];     /* v_pk_fma_f16 (neg) */  \
        half2_t p2 = u2h(h2u(t2) & 0x7FFF7FFFu);     /* packed |t| */          \
        a_ = fdot2_(p2, kOne, a_);                   /* f32 accumulate */      \
      }                                                                        \
      acc[x] = a_;                                                             \
    }                                                                          \
  }

  COMPUTE_CHUNK(0)

  // chunk-1 writes: vmcnt for p0..s1v drained long ago under compute
  WRITE_CHUNK(1, p0, p1, s0v, s1v)

  __syncthreads();   // bar1: buf1 ready

  COMPUTE_CHUNK(1)

  float tsum = 0.0f;
#pragma unroll
  for (int x = 0; x < 8; ++x) tsum += acc[x];

  for (int off = 32; off > 0; off >>= 1) tsum += __shfl_down(tsum, off, 64);

  const int wid = tid >> 6;
  if ((tid & 63) == 0) wsum[wid] = tsum;
  __syncthreads();
  if (tid == 0)
    atomicAdd(out, (wsum[0] + wsum[1] + wsum[2] + wsum[3]) * SCALE);

#undef WRITE_CHUNK
#undef COMPUTE_CHUNK
}

// ---------------- f32 fallback (no workspace): R4 structure ----------------
#define FCT    64
#define FSTR   132
#define FCSPL  4
#define FNCOLB 16

__global__ __launch_bounds__(256, 2) void work_f32_fallback(const float* __restrict__ logits,
                                                            const int* __restrict__ masks,
                                                            float* __restrict__ out) {
  __shared__ __align__(16) float tA[FCT][FSTR];
  __shared__ __align__(16) float tB[FCT][FSTR];
  __shared__ float wsum[4];

  const int tid = threadIdx.x;
  const int bid = blockIdx.x;

  if (bid < FNCOLB) {
    const int s    = bid >> 1;
    const int half = bid & 1;
    const int c    = half * 256 + tid;
    const int bb   = s >> 2;
    const int r    = s & 3;
    const int* mrow = masks + bb * N;
    float mc = (mrow[c] > 0) ? 1.0f : 0.0f;
    float sum = 0.0f;
#pragma unroll 4
    for (int a = 0; a < N; ++a) {
      float ma = (mrow[a] > 0) ? 1.0f : 0.0f;
      size_t idx = ((size_t)(bb * N + a) * N + c) * RNUM + r;
      sum += sigmoidf_(logits[idx]) * ma * mc;
    }
    float v = sum * ((float)N - sum);
    for (int off = 32; off > 0; off >>= 1) v += __shfl_down(v, off, 64);
    const int wid = tid >> 6;
    if ((tid & 63) == 0) wsum[wid] = v;
    __syncthreads();
    if (tid == 0)
      atomicAdd(out, (wsum[0] + wsum[1] + wsum[2] + wsum[3]) * SCALE);
    return;
  }

  const int m  = bid - FNCOLB;
  const int bt = m & 3;
  const int at = (m >> 2) & 3;
  const int s  = (m >> 4) & 7;
  const int cz = m >> 7;
  const int a0 = at * TILE;
  const int b0 = bt * TILE;
  const int bb = s >> 2;
  const int r  = s & 3;
  const int cbeg = cz * (N / FCSPL);
  const int cend = cbeg + (N / FCSPL);

  const int ta = tid & 15;
  const int tb = tid >> 4;
  const int* mrow = masks + bb * N;

  float rab[8][8];
#pragma unroll
  for (int x = 0; x < 8; ++x) {
    int ra = a0 + ((x >> 2) << 6) + ta * 4 + (x & 3);
    float ma = (mrow[ra] > 0) ? 1.0f : 0.0f;
#pragma unroll
    for (int y = 0; y < 8; ++y) {
      int cb = b0 + ((y >> 2) << 6) + tb * 4 + (y & 3);
      float mb = (mrow[cb] > 0) ? 1.0f : 0.0f;
      size_t idx = ((size_t)(bb * N + ra) * N + cb) * RNUM + r;
      rab[x][y] = sigmoidf_(logits[idx]) * ma * mb;
    }
  }

  float acc[8][2];
#pragma unroll
  for (int x = 0; x < 8; ++x) { acc[x][0] = 0.0f; acc[x][1] = 0.0f; }

  for (int c0 = cbeg; c0 < cend; c0 += FCT) {
    __syncthreads();
#pragma unroll
    for (int it = 0; it < 32; ++it) {
      int e = it * 256 + tid;
      int c = e & 63;
      int i = e >> 6;
      int pc = ((((i >> 2) ^ ((c >> 2) & 31)) & 31) << 2) | (i & 3);
      float mc = (mrow[c0 + c] > 0) ? 1.0f : 0.0f;
      {
        float mi = (mrow[a0 + i] > 0) ? 1.0f : 0.0f;
        size_t idx = ((size_t)(bb * N + a0 + i) * N + (c0 + c)) * RNUM + r;
        tA[c][pc] = sigmoidf_(logits[idx]) * mi * mc;
      }
      {
        float mi = (mrow[b0 + i] > 0) ? 1.0f : 0.0f;
        size_t idx = ((size_t)(bb * N + b0 + i) * N + (c0 + c)) * RNUM + r;
        tB[c][pc] = sigmoidf_(logits[idx]) * mi * mc;
      }
    }
    __syncthreads();

#pragma unroll 2
    for (int cg = 0; cg < FCT / 4; ++cg) {
      const float* pa = &tA[cg * 4][((ta ^ cg) & 31) << 2];
      const float* pb = &tB[cg * 4][((tb ^ cg) & 31) << 2];
#pragma unroll
      for (int dc = 0; dc < 4; ++dc) {
        float4 a0v = *(const float4*)(pa + dc * FSTR);
        float4 a1v = *(const float4*)(pa + dc * FSTR + 64);
        float4 b0v = *(const float4*)(pb + dc * FSTR);
        float4 b1v = *(const float4*)(pb + dc * FSTR + 64);
        float avv[8] = {a0v.x, a0v.y, a0v.z, a0v.w, a1v.x, a1v.y, a1v.z, a1v.w};
        float bvv[8] = {b0v.x, b0v.y, b0v.z, b0v.w, b1v.x, b1v.y, b1v.z, b1v.w};
#pragma unroll
        for (int x = 0; x < 8; ++x) {
#pragma unroll
          for (int y = 0; y < 4; ++y)
            acc[x][0] += fabsf(fmaf(-avv[x], bvv[y], rab[x][y]));
#pragma unroll
          for (int y = 4; y < 8; ++y)
            acc[x][1] += fabsf(fmaf(-avv[x], bvv[y], rab[x][y]));
        }
      }
    }
  }

  float tsum = 0.0f;
#pragma unroll
  for (int x = 0; x < 8; ++x) tsum += acc[x][0] + acc[x][1];
  for (int off = 32; off > 0; off >>= 1) tsum += __shfl_down(tsum, off, 64);
  const int wid = tid >> 6;
  if ((tid & 63) == 0) wsum[wid] = tsum;
  __syncthreads();
  if (tid == 0)
    atomicAdd(out, (wsum[0] + wsum[1] + wsum[2] + wsum[3]) * SCALE);
}

extern "C" void kernel_launch(void* const* d_in, const int* in_sizes, int n_in,
                              void* d_out, int out_size, void* d_ws, size_t ws_size,
                              hipStream_t stream) {
  const float* logits = (const float*)d_in[0];
  const int*   masks  = (const int*)d_in[1];
  float*       out    = (float*)d_out;

  const size_t P_BYTES = (size_t)NSLICE * N * N * sizeof(_Float16);  // 4 MB

  if (ws_size >= P_BYTES) {
    _Float16* P = (_Float16*)d_ws;
    prep_f16_kernel<<<(BNUM * N * N / 4) / 256, 256, 0, stream>>>(logits, masks, P, out);
    const int nblocks = NCOLB + 4 * 4 * NSLICE * CSPLIT;  // 16 + 1024
    work_f16_kernel<<<nblocks, 256, 0, stream>>>(P, out);
  } else {
    zero_out_kernel<<<1, 1, 0, stream>>>(out);
    const int nblocks = FNCOLB + 4 * 4 * NSLICE * FCSPL;  // 16 + 512
    work_f32_fallback<<<nblocks, 256, 0, stream>>>(logits, masks, out);
  }
}